// Round 9
// baseline (273.613 us; speedup 1.0000x reference)
//
#include <hip/hip_runtime.h>
#include <stdint.h>

#define T_STEPS 8
#define N_NODES 100000
#define E_EDGES 3200000
#define NB1 250
#define CHUNK 400          // NB1*CHUNK == N_NODES
#define NB3 391            // ceil(N/256)
#define NCAND_T 4000       // NB1*16 per t
#define NSLICE 8
#define ESLICE (E_EDGES / NSLICE)   // 400000
#define NRNG 4                      // owner r = row & 3
#define ACCN 25000                  // rows per owner: 100000/4 -> 100 KB LDS
#define SC_BLKS (T_STEPS * NRNG * NSLICE)  // 256 = 1 block/CU

// ---- bf16 pack/unpack (RNE) ----
__device__ __forceinline__ uint16_t f2bf(float x) {
    uint32_t b = __float_as_uint(x);
    b += 0x7FFFu + ((b >> 16) & 1u);
    return (uint16_t)(b >> 16);
}
__device__ __forceinline__ float bf2f(uint16_t u) {
    return __uint_as_float(((uint32_t)u) << 16);
}

// ---- sortable key: value desc, tie -> lower index ----
__device__ __forceinline__ unsigned long long make_key(float v, int idx) {
    uint32_t u = __float_as_uint(v);
    u = (u & 0x80000000u) ? ~u : (u | 0x80000000u);
    return (((unsigned long long)u) << 32) | (unsigned long long)(~(uint32_t)idx);
}
__device__ __forceinline__ float key_val(unsigned long long k) {
    uint32_t u = (uint32_t)(k >> 32);
    u = (u & 0x80000000u) ? (u & 0x7FFFFFFFu) : ~u;
    return __uint_as_float(u);
}
__device__ __forceinline__ int key_idx(unsigned long long k) {
    return (int)(~(uint32_t)(k & 0xFFFFFFFFu));
}

__device__ __forceinline__ unsigned long long shfl_xor_u64(unsigned long long x, int mask) {
    uint32_t lo = (uint32_t)x, hi = (uint32_t)(x >> 32);
    lo = __shfl_xor((unsigned int)lo, mask);
    hi = __shfl_xor((unsigned int)hi, mask);
    return (((unsigned long long)hi) << 32) | lo;
}

__device__ __forceinline__ void wave_argmax(unsigned long long& m, int& mp) {
    #pragma unroll
    for (int off = 32; off; off >>= 1) {
        unsigned long long o = shfl_xor_u64(m, off);
        int op = __shfl_xor(mp, off);
        if (o > m) { m = o; mp = op; }
    }
}

__device__ __forceinline__ float dot16(const float4* __restrict__ xr, const float* w) {
    float4 a = xr[0], b = xr[1], c = xr[2], d = xr[3];
    return a.x*w[0] + a.y*w[1] + a.z*w[2] + a.w*w[3]
         + b.x*w[4] + b.y*w[5] + b.z*w[6] + b.w*w[7]
         + c.x*w[8] + c.y*w[9] + c.z*w[10] + c.w*w[11]
         + d.x*w[12] + d.y*w[13] + d.z*w[14] + d.w*w[15];
}

// K1: for all t — y = (X_t @ p)/||p||, per-block top-16 candidates (sorted desc).
__global__ __launch_bounds__(256) void k_y_topk_all(const float* __restrict__ X,
                                                    const float* __restrict__ p,
                                                    unsigned long long* __restrict__ cand) {
    __shared__ unsigned long long keys[CHUNK];
    __shared__ unsigned long long wm[4];
    __shared__ int wp[4];
    int tid = threadIdx.x;
    int t = blockIdx.x / NB1;
    int b = blockIdx.x % NB1;
    const float* Xt = X + (size_t)t * N_NODES * 16;
    float pv[16];
    #pragma unroll
    for (int i = 0; i < 16; i++) pv[i] = p[i];
    float pn = 0.f;
    #pragma unroll
    for (int i = 0; i < 16; i++) pn += pv[i] * pv[i];
    float inv = 1.0f / sqrtf(pn);
    int base = b * CHUNK;
    for (int i = tid; i < CHUNK; i += 256) {
        int n = base + i;
        float y = dot16((const float4*)(Xt + (size_t)n * 16), pv) * inv;
        keys[i] = make_key(y, n);
    }
    __syncthreads();
    for (int k = 0; k < 16; k++) {
        unsigned long long m = 0ULL; int mp = -1;
        for (int i = tid; i < CHUNK; i += 256) {
            unsigned long long v = keys[i];
            if (v > m) { m = v; mp = i; }
        }
        wave_argmax(m, mp);
        if ((tid & 63) == 0) { wm[tid >> 6] = m; wp[tid >> 6] = mp; }
        __syncthreads();
        if (tid == 0) {
            unsigned long long best = wm[0]; int bp = wp[0];
            #pragma unroll
            for (int w2 = 1; w2 < 4; w2++) if (wm[w2] > best) { best = wm[w2]; bp = wp[w2]; }
            cand[(size_t)t * NCAND_T + b * 16 + k] = best;
            keys[bp] = 0ULL;
        }
        __syncthreads();
    }
}

// K2: one block, 512 threads = 8 waves. Wave w merges t=w's 250 sorted lists
// (k-way merge, heads in registers). Then batch-prefetch all Xs, then GRU chain.
__global__ __launch_bounds__(512) void k_merge_gru(
    const unsigned long long* __restrict__ cand,   // [8][4000]
    const float* __restrict__ X,                   // [8][N][16]
    const float* __restrict__ Winit,
    const float* __restrict__ W_Z, const float* __restrict__ U_Z, const float* __restrict__ B_Z,
    const float* __restrict__ W_R, const float* __restrict__ U_R, const float* __restrict__ B_R,
    const float* __restrict__ W_H, const float* __restrict__ U_H, const float* __restrict__ B_H,
    const float* __restrict__ lin_w,
    float* __restrict__ weff_g) {                  // [8][16]
    __shared__ float mWZ[256], mUZ[256], mBZ[256], mWR[256], mUR[256], mBR[256];
    __shared__ float mWH[256], mUH[256], mBH[256], mLW[16];
    __shared__ int   sidx[8][16];
    __shared__ float sval[8][16];
    __shared__ float Xs_all[8][16][16];   // [t][f][k]
    __shared__ float Wcur[16][16];
    __shared__ float RgW[16][16];
    int tid = threadIdx.x;
    if (tid < 256) {
        mWZ[tid] = W_Z[tid]; mUZ[tid] = U_Z[tid]; mBZ[tid] = B_Z[tid];
        mWR[tid] = W_R[tid]; mUR[tid] = U_R[tid]; mBR[tid] = B_R[tid];
        mWH[tid] = W_H[tid]; mUH[tid] = U_H[tid]; mBH[tid] = B_H[tid];
        Wcur[tid >> 4][tid & 15] = Winit[tid];
        if (tid < 16) mLW[tid] = lin_w[tid];
    }
    {
        int w = tid >> 6, lane = tid & 63;
        const unsigned long long* ct = cand + (size_t)w * NCAND_T;
        int cb = lane * 4;
        unsigned long long h0 = 0, h1 = 0, h2 = 0, h3 = 0;
        int p0 = 0, p1 = 0, p2 = 0, p3 = 0;
        if (cb + 0 < NB1) h0 = ct[(cb + 0) * 16];
        if (cb + 1 < NB1) h1 = ct[(cb + 1) * 16];
        if (cb + 2 < NB1) h2 = ct[(cb + 2) * 16];
        if (cb + 3 < NB1) h3 = ct[(cb + 3) * 16];
        for (int k = 0; k < 16; k++) {
            unsigned long long m = h0; int pay = (lane << 2) | 0;
            if (h1 > m) { m = h1; pay = (lane << 2) | 1; }
            if (h2 > m) { m = h2; pay = (lane << 2) | 2; }
            if (h3 > m) { m = h3; pay = (lane << 2) | 3; }
            wave_argmax(m, pay);
            if (lane == 0) { sidx[w][k] = key_idx(m); sval[w][k] = key_val(m); }
            if ((pay >> 2) == lane) {
                switch (pay & 3) {
                case 0: p0++; h0 = (p0 < 16) ? ct[(cb + 0) * 16 + p0] : 0ULL; break;
                case 1: p1++; h1 = (p1 < 16) ? ct[(cb + 1) * 16 + p1] : 0ULL; break;
                case 2: p2++; h2 = (p2 < 16) ? ct[(cb + 2) * 16 + p2] : 0ULL; break;
                default: p3++; h3 = (p3 < 16) ? ct[(cb + 3) * 16 + p3] : 0ULL; break;
                }
            }
        }
    }
    __syncthreads();
    // batched Xs prefetch for ALL t: 2048 scattered loads in flight at once
    for (int e = tid; e < 8 * 256; e += 512) {
        int tt = e >> 8, kk = (e >> 4) & 15, ff = e & 15;
        Xs_all[tt][ff][kk] = X[(size_t)tt * N_NODES * 16 + (size_t)sidx[tt][kk] * 16 + ff]
                           * sval[tt][kk];
    }
    __syncthreads();
    int i = (tid & 255) >> 4, j = tid & 15;
    for (int t = 0; t < T_STEPS; t++) {
        float Zg = 0.f, wn = 0.f;
        if (tid < 256) {
            float az = 0.f, ar = 0.f, uz = 0.f, ur = 0.f;
            #pragma unroll
            for (int m = 0; m < 16; m++) {
                az += mWZ[i * 16 + m] * Xs_all[t][m][j];
                ar += mWR[i * 16 + m] * Xs_all[t][m][j];
                uz += mUZ[i * 16 + m] * Wcur[m][j];
                ur += mUR[i * 16 + m] * Wcur[m][j];
            }
            Zg = 1.0f / (1.0f + expf(-(az + uz + mBZ[i * 16 + j])));
            float Rg = 1.0f / (1.0f + expf(-(ar + ur + mBR[i * 16 + j])));
            RgW[i][j] = Rg * Wcur[i][j];
        }
        __syncthreads();
        if (tid < 256) {
            float ah = 0.f, uh = 0.f;
            #pragma unroll
            for (int m = 0; m < 16; m++) {
                ah += mWH[i * 16 + m] * Xs_all[t][m][j];
                uh += mUH[i * 16 + m] * RgW[m][j];
            }
            float Ht = tanhf(ah + uh + mBH[i * 16 + j]);
            wn = (1.0f - Zg) * Wcur[i][j] + Zg * Ht;
        }
        __syncthreads();
        if (tid < 256) Wcur[i][j] = wn;
        __syncthreads();
        if (tid < 16) {
            float acc = 0.f;
            #pragma unroll
            for (int jj = 0; jj < 16; jj++) acc += Wcur[tid][jj] * mLW[jj];
            weff_g[t * 16 + tid] = acc;
        }
        __syncthreads();
    }
}

// K3: s[t][n] = X_t[n,:] . w_eff[t]
__global__ __launch_bounds__(256) void k_s_all(const float* __restrict__ X,
                                               const float* __restrict__ weff,
                                               float* __restrict__ s) {
    int t = blockIdx.x / NB3;
    int b = blockIdx.x % NB3;
    __shared__ float w[16];
    if (threadIdx.x < 16) w[threadIdx.x] = weff[t * 16 + threadIdx.x];
    __syncthreads();
    int n = b * 256 + threadIdx.x;
    if (n < N_NODES) {
        float v = dot16((const float4*)(X + ((size_t)t * N_NODES + n) * 16), w);
        s[(size_t)t * N_NODES + n] = v;
    }
}

// K4: fused LDS scatter with interleaved ownership (r = row&3, local = row>>2)
// and a 3-stage cross-iteration software pipeline:
//   iter k: [A] prefetch streams salvo k+2  [B] gathers salvo k+1  [C] ds_adds salvo k
// Loop-carried named registers make the prefetch un-sinkable; sched_barrier(0)
// separates stages. Gathers and adds are PREDICATED (~16/64 lanes).
extern "C" __global__ __launch_bounds__(1024) void k_scatter_fused(
    const int* __restrict__ erow, const int* __restrict__ ecol,
    const float* __restrict__ evalv, const float* __restrict__ s,
    uint16_t* __restrict__ rep) {
    extern __shared__ float acc[];   // ACCN floats
    const int bid = blockIdx.x;
    const int t = bid & 7;           // one t per XCD (round-robin dispatch)
    const int m = bid >> 3;          // 0..31
    const int slice = m >> 2;        // 0..7
    const int r = m & 3;             // owner lane: row & 3 == r
    const int tid = threadIdx.x;
    for (int i = tid; i < ACCN; i += 1024) acc[i] = 0.f;
    __syncthreads();
    const float* __restrict__ st = s + (size_t)t * N_NODES;
    const size_t eb = (size_t)t * E_EDGES + (size_t)slice * ESLICE;
    const int4* __restrict__ r4 = (const int4*)(erow + eb);
    const int4* __restrict__ c4 = (const int4*)(ecol + eb);
    const float4* __restrict__ v4 = (const float4*)(evalv + eb);
    const int n4 = ESLICE / 4;       // 100000 packets
    const int S = (n4 + 1023) >> 10; // 98 salvos (uniform across threads)

    // ---- prologue: load salvo 0 and salvo 1; gather salvo 0 ----
    int j0 = tid;
    int j1 = tid + 1024;
    int jc0 = j0 < n4 ? j0 : n4 - 1;
    int jc1 = j1 < n4 ? j1 : n4 - 1;
    int4   R1 = r4[jc0]; int4 C1 = c4[jc0]; float4 V1 = v4[jc0];
    int4   R2 = r4[jc1]; int4 C2 = c4[jc1]; float4 V2 = v4[jc1];
    bool va0 = (j0 < n4) && ((R1.x & 3) == r);
    bool va1 = (j0 < n4) && ((R1.y & 3) == r);
    bool va2 = (j0 < n4) && ((R1.z & 3) == r);
    bool va3 = (j0 < n4) && ((R1.w & 3) == r);
    int  la0 = R1.x >> 2, la1 = R1.y >> 2, la2 = R1.z >> 2, la3 = R1.w >> 2;
    float ga0 = va0 ? st[C1.x] : 0.f;
    float ga1 = va1 ? st[C1.y] : 0.f;
    float ga2 = va2 ? st[C1.z] : 0.f;
    float ga3 = va3 ? st[C1.w] : 0.f;

    #pragma unroll 1
    for (int k = 0; k < S; ++k) {
        // ---- stage A: prefetch streams for salvo k+2 ----
        int jn = tid + ((k + 2) << 10);
        int jcn = jn < n4 ? jn : n4 - 1;
        int4   Rn = r4[jcn]; int4 Cn = c4[jcn]; float4 Vn = v4[jcn];
        __builtin_amdgcn_sched_barrier(0);
        // ---- stage B: gathers for salvo k+1 (from R2/C2 loaded last iter) ----
        bool vok = (tid + ((k + 1) << 10)) < n4;
        bool vb0 = vok && ((R2.x & 3) == r);
        bool vb1 = vok && ((R2.y & 3) == r);
        bool vb2 = vok && ((R2.z & 3) == r);
        bool vb3 = vok && ((R2.w & 3) == r);
        int  lb0 = R2.x >> 2, lb1 = R2.y >> 2, lb2 = R2.z >> 2, lb3 = R2.w >> 2;
        float gb0 = vb0 ? st[C2.x] : 0.f;
        float gb1 = vb1 ? st[C2.y] : 0.f;
        float gb2 = vb2 ? st[C2.z] : 0.f;
        float gb3 = vb3 ? st[C2.w] : 0.f;
        __builtin_amdgcn_sched_barrier(0);
        // ---- stage C: LDS atomic adds for salvo k (gathered last iter) ----
        if (va0) atomicAdd(&acc[la0], V1.x * ga0);
        if (va1) atomicAdd(&acc[la1], V1.y * ga1);
        if (va2) atomicAdd(&acc[la2], V1.z * ga2);
        if (va3) atomicAdd(&acc[la3], V1.w * ga3);
        // ---- rotate ----
        va0 = vb0; va1 = vb1; va2 = vb2; va3 = vb3;
        la0 = lb0; la1 = lb1; la2 = lb2; la3 = lb3;
        ga0 = gb0; ga1 = gb1; ga2 = gb2; ga3 = gb3;
        V1 = V2;
        R2 = Rn; C2 = Cn; V2 = Vn;
    }
    __syncthreads();
    const int seg = t * 32 + m;
    uint16_t* rp = rep + (size_t)seg * ACCN;
    for (int i = tid; i < ACCN; i += 1024) rp[i] = f2bf(acc[i]);
}

// K5: out[t][n] = lin_b + sum_slices rep ; owner r = n&3, local = n>>2
__global__ __launch_bounds__(256) void k_reduce_full(const uint16_t* __restrict__ rep,
                                                     const float* __restrict__ lin_b,
                                                     float* __restrict__ out) {
    int t = blockIdx.x / NB3;
    int b = blockIdx.x % NB3;
    int n = b * 256 + threadIdx.x;
    if (n >= N_NODES) return;
    int r = n & 3;
    int local = n >> 2;
    float acc = lin_b[0];
    #pragma unroll
    for (int sl = 0; sl < NSLICE; sl++) {
        int seg = t * 32 + sl * 4 + r;
        acc += bf2f(rep[(size_t)seg * ACCN + local]);
    }
    out[(size_t)t * N_NODES + n] = acc;
}

extern "C" void kernel_launch(void* const* d_in, const int* in_sizes, int n_in,
                              void* d_out, int out_size, void* d_ws, size_t ws_size,
                              hipStream_t stream) {
    const float* X     = (const float*)d_in[0];
    const int*   erow  = (const int*)d_in[1];
    const int*   ecol  = (const int*)d_in[2];
    const float* evalv = (const float*)d_in[3];
    const float* p     = (const float*)d_in[4];
    const float* W_Z   = (const float*)d_in[5];
    const float* U_Z   = (const float*)d_in[6];
    const float* B_Z   = (const float*)d_in[7];
    const float* W_R   = (const float*)d_in[8];
    const float* U_R   = (const float*)d_in[9];
    const float* B_R   = (const float*)d_in[10];
    const float* W_H   = (const float*)d_in[11];
    const float* U_H   = (const float*)d_in[12];
    const float* B_H   = (const float*)d_in[13];
    const float* Winit = (const float*)d_in[14];
    const float* lin_w = (const float*)d_in[15];
    const float* lin_b = (const float*)d_in[16];
    float* out = (float*)d_out;

    size_t dynLDS = (size_t)ACCN * sizeof(float);   // 100 KB
    (void)hipFuncSetAttribute((const void*)k_scatter_fused,
                              hipFuncAttributeMaxDynamicSharedMemorySize,
                              (int)dynLDS);

    char* ws = (char*)d_ws;
    float* s    = (float*)ws;                                       // 3,200,000 B
    float* weff = (float*)(ws + 3200000);                           // 512 B
    unsigned long long* cand = (unsigned long long*)(ws + 3201024); // 256,000 B
    uint16_t* rep = (uint16_t*)(ws + 3457024);                      // 256*25000*2 = 12.8 MB

    k_y_topk_all<<<T_STEPS * NB1, 256, 0, stream>>>(X, p, cand);
    k_merge_gru<<<1, 512, 0, stream>>>(cand, X, Winit,
                                       W_Z, U_Z, B_Z, W_R, U_R, B_R, W_H, U_H, B_H,
                                       lin_w, weff);
    k_s_all<<<T_STEPS * NB3, 256, 0, stream>>>(X, weff, s);
    k_scatter_fused<<<SC_BLKS, 1024, dynLDS, stream>>>(erow, ecol, evalv, s, rep);
    k_reduce_full<<<T_STEPS * NB3, 256, 0, stream>>>(rep, lin_b, out);
}